// Round 7
// baseline (495.249 us; speedup 1.0000x reference)
//
#include <hip/hip_runtime.h>
#include <hip/hip_bf16.h>

#define IN_F 1024
#define OUT_F 1024
#define QP 9                   // silu + 8 spline bases per input feature
#define KDIM (IN_F * QP)       // 9216
#define SPLITK 3
#define KSLICE (KDIM / SPLITK) // 3072 = 48 * 64
#define BK 64

typedef __attribute__((ext_vector_type(8)))  short short8;           // MFMA A/B frag (8 bf16)
typedef __attribute__((ext_vector_type(16))) float floatx16;         // 32x32 MFMA C/D frag
typedef __attribute__((ext_vector_type(8)))  unsigned short ushort8v;// 16B bf16 store

__device__ __forceinline__ unsigned short f2bf(float f) {
    union { float f; unsigned u; } v; v.f = f;
    return (unsigned short)((v.u + 0x7FFF + ((v.u >> 16) & 1)) >> 16); // RNE
}

// ============ fused pack: A [B,KDIM] + W [OUT,KDIM], bf16; k = s*IN_F + i ============
// Uniform grid linspace(-1,1,12) -> cardinal cubic: u=(x+1)*5.5, t=frac(u), 4 weights.
__global__ __launch_bounds__(256) void pack_kernel(const float* __restrict__ x,
                                                   const float* __restrict__ bw,
                                                   const float* __restrict__ sw,
                                                   __hip_bfloat16* __restrict__ A,
                                                   __hip_bfloat16* __restrict__ W, int Bm) {
    const int nb_a = (Bm * IN_F / 8) / 256;
    if ((int)blockIdx.x < nb_a) {
        int t  = blockIdx.x * 256 + threadIdx.x;   // one thread = 8 features of one row
        int b  = t >> 7;
        int i0 = (t & 127) * 8;
        const float4* xr = (const float4*)(x + (size_t)b * IN_F + i0);
        float4 x0 = xr[0], x1 = xr[1];
        float xv[8] = {x0.x, x0.y, x0.z, x0.w, x1.x, x1.y, x1.z, x1.w};
        ushort8v ov[9];
#pragma unroll
        for (int e = 0; e < 8; ++e) {
            float v  = xv[e];
            float u  = (v + 1.0f) * 5.5f;
            float fj = floorf(u);
            int   j  = (int)fj;
            float tt = u - fj;
            float t2 = tt * tt, t3 = t2 * tt;
            float omt = 1.0f - tt;
            float w0 = omt * omt * omt * (1.0f / 6.0f);                           // q=j-3
            float w1 = (3.0f * t3 - 6.0f * t2 + 4.0f) * (1.0f / 6.0f);            // q=j-2
            float w2 = (-3.0f * t3 + 3.0f * t2 + 3.0f * tt + 1.0f) * (1.0f/6.0f); // q=j-1
            float w3 = t3 * (1.0f / 6.0f);                                        // q=j
            ov[0][e] = f2bf(v * __builtin_amdgcn_rcpf(1.0f + __expf(-v)));        // silu
#pragma unroll
            for (int q = 0; q < 8; ++q) {
                int d = j - q;
                float bv = (d == 3) ? w0 : (d == 2) ? w1 : (d == 1) ? w2 : (d == 0) ? w3 : 0.0f;
                ov[1 + q][e] = f2bf(bv);
            }
        }
        unsigned short* dst = (unsigned short*)A + (size_t)b * KDIM + i0;
#pragma unroll
        for (int s = 0; s < QP; ++s)
            *(ushort8v*)(dst + (size_t)s * IN_F) = ov[s];        // coalesced 16B
    } else {
        int t = ((int)blockIdx.x - nb_a) * 256 + threadIdx.x;    // one (o,i)
        unsigned short* dst = (unsigned short*)W + (size_t)(t >> 10) * KDIM + (t & 1023);
        dst[0] = f2bf(bw[t]);
        const float4* s4 = (const float4*)(sw + (size_t)t * 8);  // 32B contiguous/thread
        float4 lo = s4[0], hi = s4[1];
        dst[1 * IN_F] = f2bf(lo.x); dst[2 * IN_F] = f2bf(lo.y);
        dst[3 * IN_F] = f2bf(lo.z); dst[4 * IN_F] = f2bf(lo.w);
        dst[5 * IN_F] = f2bf(hi.x); dst[6 * IN_F] = f2bf(hi.y);
        dst[7 * IN_F] = f2bf(hi.z); dst[8 * IN_F] = f2bf(hi.w);  // coalesced across lanes
    }
}

// ============ split-K GEMM: 128x128 tile, BK=64, 32x32x16 MFMA ============
// Register-staged single-LDS double buffer: tile k+1 is loaded global->VGPR while
// the MFMA block of tile k runs (loads consumed only by next iter's ds_write ->
// no vmcnt(0)-before-compute, unlike global_load_lds). 3 blocks/CU (launch_bounds
// 256,3; 32 KB LDS -> 96 KB/CU). 3-bit XOR swizzle keeps frag ds_read_b128 2-way.
__global__ __launch_bounds__(256, 3) void gemm_splitk(const __hip_bfloat16* __restrict__ A,
                                                      const __hip_bfloat16* __restrict__ W,
                                                      float* __restrict__ P, int Bm) {
    __shared__ short sA[128 * BK];   // 16 KB
    __shared__ short sB[128 * BK];   // 16 KB
    const int tid   = threadIdx.x;
    const int lane  = tid & 63;
    const int wave  = tid >> 6;
    const int row32 = lane & 31;
    const int half  = lane >> 5;                 // k-half within a 32x32x16 frag
    const int wm = wave >> 1, wn = wave & 1;     // 2x2 waves, each 64x64
    const int m0 = blockIdx.y * 128;
    const int n0 = blockIdx.x * 128;
    const int kb = blockIdx.z * KSLICE;

    const short* Ag = (const short*)A + (size_t)m0 * KDIM + kb;
    const short* Wg = (const short*)W + (size_t)n0 * KDIM + kb;

    floatx16 acc[2][2] = {};

    // staging geometry: 16B chunk c = p*256+tid; row rs=c>>3; lds col q=c&7 holds
    // global chunk q ^ ((rs>>1)&7); ds_write addr = c*16 B (lane-contiguous).
    int rs[4], ko[4], ld[4];
#pragma unroll
    for (int p = 0; p < 4; ++p) {
        int c = p * 256 + tid;
        rs[p] = c >> 3;
        ko[p] = (((c & 7) ^ ((rs[p] >> 1) & 7)) * 8);
        ld[p] = c * 8;
    }

    // frag rows + swizzle bases
    const int rA0 = wm * 64 + row32, rA1 = rA0 + 32;
    const int rB0 = wn * 64 + row32, rB1 = rB0 + 32;
    const int swA0 = (rA0 >> 1) & 7, swA1 = (rA1 >> 1) & 7;
    const int swB0 = (rB0 >> 1) & 7, swB1 = (rB1 >> 1) & 7;

    // preload tile 0 into registers
    uint4 gA[4], gB[4];
#pragma unroll
    for (int p = 0; p < 4; ++p) {
        gA[p] = *(const uint4*)(Ag + (size_t)rs[p] * KDIM + ko[p]);
        gB[p] = *(const uint4*)(Wg + (size_t)rs[p] * KDIM + ko[p]);
    }

    for (int k0 = 0; k0 < KSLICE; k0 += BK) {
        __syncthreads();                         // prev-iter LDS readers done
#pragma unroll
        for (int p = 0; p < 4; ++p) {
            *(uint4*)(sA + ld[p]) = gA[p];
            *(uint4*)(sB + ld[p]) = gB[p];
        }
        __syncthreads();

        if (k0 + BK < KSLICE) {                  // prefetch next tile -> regs
#pragma unroll
            for (int p = 0; p < 4; ++p) {
                gA[p] = *(const uint4*)(Ag + (size_t)rs[p] * KDIM + k0 + BK + ko[p]);
                gB[p] = *(const uint4*)(Wg + (size_t)rs[p] * KDIM + k0 + BK + ko[p]);
            }
        }

#pragma unroll
        for (int ks = 0; ks < 4; ++ks) {         // four K=16 steps per staging iter
            int c = ks * 2 + half;
            short8 aF[2], bF[2];
            aF[0] = *(const short8*)&sA[rA0 * BK + ((c ^ swA0) * 8)];
            aF[1] = *(const short8*)&sA[rA1 * BK + ((c ^ swA1) * 8)];
            bF[0] = *(const short8*)&sB[rB0 * BK + ((c ^ swB0) * 8)];
            bF[1] = *(const short8*)&sB[rB1 * BK + ((c ^ swB1) * 8)];
#pragma unroll
            for (int mi = 0; mi < 2; ++mi)
#pragma unroll
                for (int ni = 0; ni < 2; ++ni)
                    acc[mi][ni] = __builtin_amdgcn_mfma_f32_32x32x16_bf16(
                        aF[mi], bF[ni], acc[mi][ni], 0, 0, 0);
        }
    }

    // C/D layout (m74/m101-verified): col = lane&31, row = (reg&3) + 8*(reg>>2) + 4*(lane>>5)
    float* Pz = P + (size_t)blockIdx.z * Bm * OUT_F;
#pragma unroll
    for (int mi = 0; mi < 2; ++mi)
#pragma unroll
        for (int ni = 0; ni < 2; ++ni)
#pragma unroll
            for (int r = 0; r < 16; ++r) {
                int row = (r & 3) + 8 * (r >> 2) + 4 * half;
                int gm  = m0 + wm * 64 + mi * 32 + row;
                Pz[(size_t)gm * OUT_F + n0 + wn * 64 + ni * 32 + row32] = acc[mi][ni][r];
            }
}

// ============ reduce: C = P0 + P1 + P2 (float4) ============
__global__ __launch_bounds__(256) void reduce_kernel(const float4* __restrict__ P,
                                                     float4* __restrict__ C, int n4) {
    int t = blockIdx.x * 256 + threadIdx.x;
    float4 a = P[t], b = P[n4 + t], c = P[2 * n4 + t];
    float4 o;
    o.x = a.x + b.x + c.x;
    o.y = a.y + b.y + c.y;
    o.z = a.z + b.z + c.z;
    o.w = a.w + b.w + c.w;
    C[t] = o;
}

// ---- fp32 fallback (tiny ws) ----
__global__ __launch_bounds__(256) void fallback_kernel(const float* __restrict__ x,
                                                       const float* __restrict__ bw,
                                                       const float* __restrict__ sw,
                                                       const float* __restrict__ grid,
                                                       float* __restrict__ out, int Bm) {
    __shared__ float sv[256][QP + 1];
    int b = blockIdx.y;
    int o = blockIdx.x * 256 + threadIdx.x;
    float acc = 0.f;
    for (int ic = 0; ic < IN_F; ic += 256) {
        int i = ic + threadIdx.x;
        float v = x[(size_t)b * IN_F + i];
        float g[12];
        for (int j = 0; j < 12; ++j) g[j] = grid[j];
        float bb[11];
        for (int j = 0; j < 11; ++j) bb[j] = (v >= g[j] && v < g[j + 1]) ? 1.f : 0.f;
        for (int k = 1; k <= 3; ++k)
            for (int j = 0; j < 11 - k; ++j)
                bb[j] = (v - g[j]) / (g[j + k] - g[j] + 1e-8f) * bb[j]
                      + (g[j + k + 1] - v) / (g[j + k + 1] - g[j + 1] + 1e-8f) * bb[j + 1];
        __syncthreads();
        sv[threadIdx.x][0] = v / (1.f + __expf(-v));
        for (int q = 0; q < 8; ++q) sv[threadIdx.x][1 + q] = bb[q];
        __syncthreads();
        for (int ii = 0; ii < 256; ++ii) {
            int i2 = ic + ii;
            acc += sv[ii][0] * bw[(size_t)o * IN_F + i2];
            const float* swp = sw + ((size_t)o * IN_F + i2) * 8;
            for (int q = 0; q < 8; ++q) acc += sv[ii][1 + q] * swp[q];
        }
    }
    out[(size_t)b * OUT_F + o] = acc;
}

extern "C" void kernel_launch(void* const* d_in, const int* in_sizes, int n_in,
                              void* d_out, int out_size, void* d_ws, size_t ws_size,
                              hipStream_t stream) {
    const float* x    = (const float*)d_in[0];
    const float* bw   = (const float*)d_in[1];
    const float* sw   = (const float*)d_in[2];
    const float* grid = (const float*)d_in[3];
    float* out = (float*)d_out;

    const int Bm = in_sizes[0] / IN_F;                     // 4096
    const size_t a_bytes = (size_t)Bm * KDIM * sizeof(__hip_bfloat16);
    const size_t w_bytes = (size_t)OUT_F * KDIM * sizeof(__hip_bfloat16);
    const size_t p_bytes = (size_t)SPLITK * Bm * OUT_F * sizeof(float);

    if (ws_size >= a_bytes + w_bytes + p_bytes && (Bm % 128) == 0) {
        __hip_bfloat16* Apk = (__hip_bfloat16*)d_ws;
        __hip_bfloat16* Wpk = (__hip_bfloat16*)((char*)d_ws + a_bytes);
        float* P = (float*)((char*)d_ws + a_bytes + w_bytes);
        const int nb_a = (Bm * IN_F / 8) / 256;            // 2048
        const int nb_w = (OUT_F * IN_F) / 256;             // 4096
        pack_kernel<<<nb_a + nb_w, 256, 0, stream>>>(x, bw, sw, Apk, Wpk, Bm);
        gemm_splitk<<<dim3(OUT_F / 128, Bm / 128, SPLITK), 256, 0, stream>>>(Apk, Wpk, P, Bm);
        reduce_kernel<<<Bm * OUT_F / 1024, 256, 0, stream>>>((const float4*)P, (float4*)out,
                                                             Bm * OUT_F / 4);
    } else {
        fallback_kernel<<<dim3(OUT_F / 256, Bm), 256, 0, stream>>>(x, bw, sw, grid, out, Bm);
    }
}

// Round 8
// 222.529 us; speedup vs baseline: 2.2256x; 2.2256x over previous
//
#include <hip/hip_runtime.h>
#include <hip/hip_bf16.h>

#define IN_F 1024
#define OUT_F 1024
#define QP 9                   // silu + 8 spline bases per input feature
#define KDIM (IN_F * QP)       // 9216
#define SPLITK 3
#define KSLICE (KDIM / SPLITK) // 3072 = 48 * 64
#define BK 64

typedef __attribute__((ext_vector_type(8)))  short short8;           // MFMA A/B frag (8 bf16)
typedef __attribute__((ext_vector_type(16))) float floatx16;         // 32x32 MFMA C/D frag
typedef __attribute__((ext_vector_type(8)))  unsigned short ushort8v;// 16B bf16 store

__device__ __forceinline__ unsigned short f2bf(float f) {
    union { float f; unsigned u; } v; v.f = f;
    return (unsigned short)((v.u + 0x7FFF + ((v.u >> 16) & 1)) >> 16); // RNE
}

// ============ fused pack: A [B,KDIM] + W [OUT,KDIM], bf16; k = s*IN_F + i ============
// Uniform grid linspace(-1,1,12) -> cardinal cubic: u=(x+1)*5.5, t=frac(u), 4 weights.
__global__ __launch_bounds__(256) void pack_kernel(const float* __restrict__ x,
                                                   const float* __restrict__ bw,
                                                   const float* __restrict__ sw,
                                                   __hip_bfloat16* __restrict__ A,
                                                   __hip_bfloat16* __restrict__ W, int Bm) {
    const int nb_a = (Bm * IN_F / 8) / 256;
    if ((int)blockIdx.x < nb_a) {
        int t  = blockIdx.x * 256 + threadIdx.x;   // one thread = 8 features of one row
        int b  = t >> 7;
        int i0 = (t & 127) * 8;
        const float4* xr = (const float4*)(x + (size_t)b * IN_F + i0);
        float4 x0 = xr[0], x1 = xr[1];
        float xv[8] = {x0.x, x0.y, x0.z, x0.w, x1.x, x1.y, x1.z, x1.w};
        ushort8v ov[9];
#pragma unroll
        for (int e = 0; e < 8; ++e) {
            float v  = xv[e];
            float u  = (v + 1.0f) * 5.5f;
            float fj = floorf(u);
            int   j  = (int)fj;
            float tt = u - fj;
            float t2 = tt * tt, t3 = t2 * tt;
            float omt = 1.0f - tt;
            float w0 = omt * omt * omt * (1.0f / 6.0f);                           // q=j-3
            float w1 = (3.0f * t3 - 6.0f * t2 + 4.0f) * (1.0f / 6.0f);            // q=j-2
            float w2 = (-3.0f * t3 + 3.0f * t2 + 3.0f * tt + 1.0f) * (1.0f/6.0f); // q=j-1
            float w3 = t3 * (1.0f / 6.0f);                                        // q=j
            ov[0][e] = f2bf(v * __builtin_amdgcn_rcpf(1.0f + __expf(-v)));        // silu
#pragma unroll
            for (int q = 0; q < 8; ++q) {
                int d = j - q;
                float bv = (d == 3) ? w0 : (d == 2) ? w1 : (d == 1) ? w2 : (d == 0) ? w3 : 0.0f;
                ov[1 + q][e] = f2bf(bv);
            }
        }
        unsigned short* dst = (unsigned short*)A + (size_t)b * KDIM + i0;
#pragma unroll
        for (int s = 0; s < QP; ++s)
            *(ushort8v*)(dst + (size_t)s * IN_F) = ov[s];        // coalesced 16B
    } else {
        int t = ((int)blockIdx.x - nb_a) * 256 + threadIdx.x;    // one (o,i)
        unsigned short* dst = (unsigned short*)W + (size_t)(t >> 10) * KDIM + (t & 1023);
        dst[0] = f2bf(bw[t]);
        const float4* s4 = (const float4*)(sw + (size_t)t * 8);  // 32B contiguous/thread
        float4 lo = s4[0], hi = s4[1];
        dst[1 * IN_F] = f2bf(lo.x); dst[2 * IN_F] = f2bf(lo.y);
        dst[3 * IN_F] = f2bf(lo.z); dst[4 * IN_F] = f2bf(lo.w);
        dst[5 * IN_F] = f2bf(hi.x); dst[6 * IN_F] = f2bf(hi.y);
        dst[7 * IN_F] = f2bf(hi.z); dst[8 * IN_F] = f2bf(hi.w);  // coalesced across lanes
    }
}

// ============ split-K GEMM: 128x128 tile, BK=64, 32x32x16 MFMA ============
// Exactly the round-6 structure (global_load_lds w=16, single LDS buffer, 3-bit XOR
// swizzle -> frag ds_read_b128 2-way/free). Single change: SPLITK=3 -> 768 blocks
// = 3 blocks/CU (12 waves/CU co-residency for implicit MFMA/VMEM overlap).
__global__ __launch_bounds__(256, 2) void gemm_splitk(const __hip_bfloat16* __restrict__ A,
                                                      const __hip_bfloat16* __restrict__ W,
                                                      float* __restrict__ P, int Bm) {
    __shared__ short sA[128 * BK];   // 16 KB
    __shared__ short sB[128 * BK];   // 16 KB
    const int tid   = threadIdx.x;
    const int lane  = tid & 63;
    const int wave  = tid >> 6;
    const int row32 = lane & 31;
    const int half  = lane >> 5;                 // k-half within a 32x32x16 frag
    const int wm = wave >> 1, wn = wave & 1;     // 2x2 waves, each 64x64
    const int m0 = blockIdx.y * 128;
    const int n0 = blockIdx.x * 128;
    const int kb = blockIdx.z * KSLICE;

    const short* Ag = (const short*)A + (size_t)m0 * KDIM + kb;
    const short* Wg = (const short*)W + (size_t)n0 * KDIM + kb;

    floatx16 acc[2][2] = {};

    // staging: 1024 16B-chunks per matrix per iter; c = p*256+tid, row=c>>3, q=c&7
    int rs[4], ko[4], ld[4];
#pragma unroll
    for (int p = 0; p < 4; ++p) {
        int c = p * 256 + tid;
        rs[p] = c >> 3;
        ko[p] = (((c & 7) ^ ((rs[p] >> 1) & 7)) * 8);
        ld[p] = c * 8;
    }

    // frag rows + swizzle bases
    const int rA0 = wm * 64 + row32, rA1 = rA0 + 32;
    const int rB0 = wn * 64 + row32, rB1 = rB0 + 32;
    const int swA0 = (rA0 >> 1) & 7, swA1 = (rA1 >> 1) & 7;
    const int swB0 = (rB0 >> 1) & 7, swB1 = (rB1 >> 1) & 7;

    for (int k0 = 0; k0 < KSLICE; k0 += BK) {
#pragma unroll
        for (int p = 0; p < 4; ++p)
            __builtin_amdgcn_global_load_lds(
                (const __attribute__((address_space(1))) void*)(Ag + (size_t)rs[p] * KDIM + k0 + ko[p]),
                (__attribute__((address_space(3))) void*)(sA + ld[p]), 16, 0, 0);
#pragma unroll
        for (int p = 0; p < 4; ++p)
            __builtin_amdgcn_global_load_lds(
                (const __attribute__((address_space(1))) void*)(Wg + (size_t)rs[p] * KDIM + k0 + ko[p]),
                (__attribute__((address_space(3))) void*)(sB + ld[p]), 16, 0, 0);
        __syncthreads();

#pragma unroll
        for (int ks = 0; ks < 4; ++ks) {         // four K=16 steps per staging iter
            int c = ks * 2 + half;               // logical 16B chunk for this lane's frag
            short8 aF[2], bF[2];
            aF[0] = *(const short8*)&sA[rA0 * BK + ((c ^ swA0) * 8)];
            aF[1] = *(const short8*)&sA[rA1 * BK + ((c ^ swA1) * 8)];
            bF[0] = *(const short8*)&sB[rB0 * BK + ((c ^ swB0) * 8)];
            bF[1] = *(const short8*)&sB[rB1 * BK + ((c ^ swB1) * 8)];
#pragma unroll
            for (int mi = 0; mi < 2; ++mi)
#pragma unroll
                for (int ni = 0; ni < 2; ++ni)
                    acc[mi][ni] = __builtin_amdgcn_mfma_f32_32x32x16_bf16(
                        aF[mi], bF[ni], acc[mi][ni], 0, 0, 0);
        }
        __syncthreads();
    }

    // C/D layout (m74/m101-verified): col = lane&31, row = (reg&3) + 8*(reg>>2) + 4*(lane>>5)
    float* Pz = P + (size_t)blockIdx.z * Bm * OUT_F;
#pragma unroll
    for (int mi = 0; mi < 2; ++mi)
#pragma unroll
        for (int ni = 0; ni < 2; ++ni)
#pragma unroll
            for (int r = 0; r < 16; ++r) {
                int row = (r & 3) + 8 * (r >> 2) + 4 * half;
                int gm  = m0 + wm * 64 + mi * 32 + row;
                Pz[(size_t)gm * OUT_F + n0 + wn * 64 + ni * 32 + row32] = acc[mi][ni][r];
            }
}

// ============ reduce: C = P0 + P1 + P2 (float4) ============
__global__ __launch_bounds__(256) void reduce_kernel(const float4* __restrict__ P,
                                                     float4* __restrict__ C, int n4) {
    int t = blockIdx.x * 256 + threadIdx.x;
    float4 a = P[t], b = P[n4 + t], c = P[2 * n4 + t];
    float4 o;
    o.x = a.x + b.x + c.x;
    o.y = a.y + b.y + c.y;
    o.z = a.z + b.z + c.z;
    o.w = a.w + b.w + c.w;
    C[t] = o;
}

// ---- fp32 fallback (tiny ws) ----
__global__ __launch_bounds__(256) void fallback_kernel(const float* __restrict__ x,
                                                       const float* __restrict__ bw,
                                                       const float* __restrict__ sw,
                                                       const float* __restrict__ grid,
                                                       float* __restrict__ out, int Bm) {
    __shared__ float sv[256][QP + 1];
    int b = blockIdx.y;
    int o = blockIdx.x * 256 + threadIdx.x;
    float acc = 0.f;
    for (int ic = 0; ic < IN_F; ic += 256) {
        int i = ic + threadIdx.x;
        float v = x[(size_t)b * IN_F + i];
        float g[12];
        for (int j = 0; j < 12; ++j) g[j] = grid[j];
        float bb[11];
        for (int j = 0; j < 11; ++j) bb[j] = (v >= g[j] && v < g[j + 1]) ? 1.f : 0.f;
        for (int k = 1; k <= 3; ++k)
            for (int j = 0; j < 11 - k; ++j)
                bb[j] = (v - g[j]) / (g[j + k] - g[j] + 1e-8f) * bb[j]
                      + (g[j + k + 1] - v) / (g[j + k + 1] - g[j + 1] + 1e-8f) * bb[j + 1];
        __syncthreads();
        sv[threadIdx.x][0] = v / (1.f + __expf(-v));
        for (int q = 0; q < 8; ++q) sv[threadIdx.x][1 + q] = bb[q];
        __syncthreads();
        for (int ii = 0; ii < 256; ++ii) {
            int i2 = ic + ii;
            acc += sv[ii][0] * bw[(size_t)o * IN_F + i2];
            const float* swp = sw + ((size_t)o * IN_F + i2) * 8;
            for (int q = 0; q < 8; ++q) acc += sv[ii][1 + q] * swp[q];
        }
    }
    out[(size_t)b * OUT_F + o] = acc;
}

extern "C" void kernel_launch(void* const* d_in, const int* in_sizes, int n_in,
                              void* d_out, int out_size, void* d_ws, size_t ws_size,
                              hipStream_t stream) {
    const float* x    = (const float*)d_in[0];
    const float* bw   = (const float*)d_in[1];
    const float* sw   = (const float*)d_in[2];
    const float* grid = (const float*)d_in[3];
    float* out = (float*)d_out;

    const int Bm = in_sizes[0] / IN_F;                     // 4096
    const size_t a_bytes = (size_t)Bm * KDIM * sizeof(__hip_bfloat16);
    const size_t w_bytes = (size_t)OUT_F * KDIM * sizeof(__hip_bfloat16);
    const size_t p_bytes = (size_t)SPLITK * Bm * OUT_F * sizeof(float);

    if (ws_size >= a_bytes + w_bytes + p_bytes && (Bm % 128) == 0) {
        __hip_bfloat16* Apk = (__hip_bfloat16*)d_ws;
        __hip_bfloat16* Wpk = (__hip_bfloat16*)((char*)d_ws + a_bytes);
        float* P = (float*)((char*)d_ws + a_bytes + w_bytes);
        const int nb_a = (Bm * IN_F / 8) / 256;            // 2048
        const int nb_w = (OUT_F * IN_F) / 256;             // 4096
        pack_kernel<<<nb_a + nb_w, 256, 0, stream>>>(x, bw, sw, Apk, Wpk, Bm);
        gemm_splitk<<<dim3(OUT_F / 128, Bm / 128, SPLITK), 256, 0, stream>>>(Apk, Wpk, P, Bm);
        reduce_kernel<<<Bm * OUT_F / 1024, 256, 0, stream>>>((const float4*)P, (float4*)out,
                                                             Bm * OUT_F / 4);
    } else {
        fallback_kernel<<<dim3(OUT_F / 256, Bm), 256, 0, stream>>>(x, bw, sw, grid, out, Bm);
    }
}

// Round 9
// 214.973 us; speedup vs baseline: 2.3038x; 1.0351x over previous
//
#include <hip/hip_runtime.h>
#include <hip/hip_bf16.h>

#define IN_F 1024
#define OUT_F 1024
#define QP 9                   // silu + 8 spline bases per input feature
#define KDIM (IN_F * QP)       // 9216
#define SPLITK 2
#define KSLICE (KDIM / SPLITK) // 4608 = 72 * 64
#define BK 64

typedef __attribute__((ext_vector_type(8)))  short short8;           // MFMA A/B frag (8 bf16)
typedef __attribute__((ext_vector_type(16))) float floatx16;         // 32x32 MFMA C/D frag
typedef __attribute__((ext_vector_type(8)))  unsigned short ushort8v;// 16B bf16 vector

__device__ __forceinline__ unsigned short f2bf(float f) {
    union { float f; unsigned u; } v; v.f = f;
    return (unsigned short)((v.u + 0x7FFF + ((v.u >> 16) & 1)) >> 16); // RNE
}
__device__ __forceinline__ float bf2f(unsigned short h) {
    union { unsigned u; float f; } v; v.u = ((unsigned)h) << 16;
    return v.f;
}

// ============ fused pack: A [B,KDIM] + W [OUT,KDIM], bf16; k = s*IN_F + i ============
// Uniform grid linspace(-1,1,12) -> cardinal cubic: u=(x+1)*5.5, t=frac(u), 4 weights.
__global__ __launch_bounds__(256) void pack_kernel(const float* __restrict__ x,
                                                   const float* __restrict__ bw,
                                                   const float* __restrict__ sw,
                                                   __hip_bfloat16* __restrict__ A,
                                                   __hip_bfloat16* __restrict__ W, int Bm) {
    const int nb_a = (Bm * IN_F / 8) / 256;
    if ((int)blockIdx.x < nb_a) {
        int t  = blockIdx.x * 256 + threadIdx.x;   // one thread = 8 features of one row
        int b  = t >> 7;
        int i0 = (t & 127) * 8;
        const float4* xr = (const float4*)(x + (size_t)b * IN_F + i0);
        float4 x0 = xr[0], x1 = xr[1];
        float xv[8] = {x0.x, x0.y, x0.z, x0.w, x1.x, x1.y, x1.z, x1.w};
        ushort8v ov[9];
#pragma unroll
        for (int e = 0; e < 8; ++e) {
            float v  = xv[e];
            float u  = (v + 1.0f) * 5.5f;
            float fj = floorf(u);
            int   j  = (int)fj;
            float tt = u - fj;
            float t2 = tt * tt, t3 = t2 * tt;
            float omt = 1.0f - tt;
            float w0 = omt * omt * omt * (1.0f / 6.0f);                           // q=j-3
            float w1 = (3.0f * t3 - 6.0f * t2 + 4.0f) * (1.0f / 6.0f);            // q=j-2
            float w2 = (-3.0f * t3 + 3.0f * t2 + 3.0f * tt + 1.0f) * (1.0f/6.0f); // q=j-1
            float w3 = t3 * (1.0f / 6.0f);                                        // q=j
            ov[0][e] = f2bf(v * __builtin_amdgcn_rcpf(1.0f + __expf(-v)));        // silu
#pragma unroll
            for (int q = 0; q < 8; ++q) {
                int d = j - q;
                float bv = (d == 3) ? w0 : (d == 2) ? w1 : (d == 1) ? w2 : (d == 0) ? w3 : 0.0f;
                ov[1 + q][e] = f2bf(bv);
            }
        }
        unsigned short* dst = (unsigned short*)A + (size_t)b * KDIM + i0;
#pragma unroll
        for (int s = 0; s < QP; ++s)
            *(ushort8v*)(dst + (size_t)s * IN_F) = ov[s];        // coalesced 16B
    } else {
        int t = ((int)blockIdx.x - nb_a) * 256 + threadIdx.x;    // one (o,i)
        unsigned short* dst = (unsigned short*)W + (size_t)(t >> 10) * KDIM + (t & 1023);
        dst[0] = f2bf(bw[t]);
        const float4* s4 = (const float4*)(sw + (size_t)t * 8);  // 32B contiguous/thread
        float4 lo = s4[0], hi = s4[1];
        dst[1 * IN_F] = f2bf(lo.x); dst[2 * IN_F] = f2bf(lo.y);
        dst[3 * IN_F] = f2bf(lo.z); dst[4 * IN_F] = f2bf(lo.w);
        dst[5 * IN_F] = f2bf(hi.x); dst[6 * IN_F] = f2bf(hi.y);
        dst[7 * IN_F] = f2bf(hi.z); dst[8 * IN_F] = f2bf(hi.w);  // coalesced across lanes
    }
}

// ============ split-K GEMM: 128x128 tile, BK=64, 32x32x16 MFMA ============
// Round-6 structure verbatim (best measured: global_load_lds w=16, single LDS
// buffer, 3-bit XOR swizzle -> frag ds_read_b128 2-way/free, SPLITK=2 = 512
// blocks). Only change vs r6: partials P stored as bf16 (halves epilogue+reduce
// HBM traffic; partial sums O(1-3) -> adds ~0.01 absmax, threshold 0.21).
__global__ __launch_bounds__(256, 2) void gemm_splitk(const __hip_bfloat16* __restrict__ A,
                                                      const __hip_bfloat16* __restrict__ W,
                                                      unsigned short* __restrict__ P, int Bm) {
    __shared__ short sA[128 * BK];   // 16 KB
    __shared__ short sB[128 * BK];   // 16 KB
    const int tid   = threadIdx.x;
    const int lane  = tid & 63;
    const int wave  = tid >> 6;
    const int row32 = lane & 31;
    const int half  = lane >> 5;                 // k-half within a 32x32x16 frag
    const int wm = wave >> 1, wn = wave & 1;     // 2x2 waves, each 64x64
    const int m0 = blockIdx.y * 128;
    const int n0 = blockIdx.x * 128;
    const int kb = blockIdx.z * KSLICE;

    const short* Ag = (const short*)A + (size_t)m0 * KDIM + kb;
    const short* Wg = (const short*)W + (size_t)n0 * KDIM + kb;

    floatx16 acc[2][2] = {};

    // staging: 1024 16B-chunks per matrix per iter; c = p*256+tid, row=c>>3, q=c&7
    int rs[4], ko[4], ld[4];
#pragma unroll
    for (int p = 0; p < 4; ++p) {
        int c = p * 256 + tid;
        rs[p] = c >> 3;
        ko[p] = (((c & 7) ^ ((rs[p] >> 1) & 7)) * 8);
        ld[p] = c * 8;
    }

    // frag rows + swizzle bases
    const int rA0 = wm * 64 + row32, rA1 = rA0 + 32;
    const int rB0 = wn * 64 + row32, rB1 = rB0 + 32;
    const int swA0 = (rA0 >> 1) & 7, swA1 = (rA1 >> 1) & 7;
    const int swB0 = (rB0 >> 1) & 7, swB1 = (rB1 >> 1) & 7;

    for (int k0 = 0; k0 < KSLICE; k0 += BK) {
#pragma unroll
        for (int p = 0; p < 4; ++p)
            __builtin_amdgcn_global_load_lds(
                (const __attribute__((address_space(1))) void*)(Ag + (size_t)rs[p] * KDIM + k0 + ko[p]),
                (__attribute__((address_space(3))) void*)(sA + ld[p]), 16, 0, 0);
#pragma unroll
        for (int p = 0; p < 4; ++p)
            __builtin_amdgcn_global_load_lds(
                (const __attribute__((address_space(1))) void*)(Wg + (size_t)rs[p] * KDIM + k0 + ko[p]),
                (__attribute__((address_space(3))) void*)(sB + ld[p]), 16, 0, 0);
        __syncthreads();

#pragma unroll
        for (int ks = 0; ks < 4; ++ks) {         // four K=16 steps per staging iter
            int c = ks * 2 + half;               // logical 16B chunk for this lane's frag
            short8 aF[2], bF[2];
            aF[0] = *(const short8*)&sA[rA0 * BK + ((c ^ swA0) * 8)];
            aF[1] = *(const short8*)&sA[rA1 * BK + ((c ^ swA1) * 8)];
            bF[0] = *(const short8*)&sB[rB0 * BK + ((c ^ swB0) * 8)];
            bF[1] = *(const short8*)&sB[rB1 * BK + ((c ^ swB1) * 8)];
#pragma unroll
            for (int mi = 0; mi < 2; ++mi)
#pragma unroll
                for (int ni = 0; ni < 2; ++ni)
                    acc[mi][ni] = __builtin_amdgcn_mfma_f32_32x32x16_bf16(
                        aF[mi], bF[ni], acc[mi][ni], 0, 0, 0);
        }
        __syncthreads();
    }

    // C/D layout (m74/m101-verified): col = lane&31, row = (reg&3) + 8*(reg>>2) + 4*(lane>>5)
    unsigned short* Pz = P + (size_t)blockIdx.z * Bm * OUT_F;
#pragma unroll
    for (int mi = 0; mi < 2; ++mi)
#pragma unroll
        for (int ni = 0; ni < 2; ++ni)
#pragma unroll
            for (int r = 0; r < 16; ++r) {
                int row = (r & 3) + 8 * (r >> 2) + 4 * half;
                int gm  = m0 + wm * 64 + mi * 32 + row;
                Pz[(size_t)gm * OUT_F + n0 + wn * 64 + ni * 32 + row32] = f2bf(acc[mi][ni][r]);
            }
}

// ============ reduce: C = P0 + P1 (bf16 partials -> fp32 out), 8 elems/thread ====
__global__ __launch_bounds__(256) void reduce_kernel(const unsigned short* __restrict__ P,
                                                     float* __restrict__ C, int n) {
    int t  = blockIdx.x * 256 + threadIdx.x;
    int i0 = t * 8;
    ushort8v a = *(const ushort8v*)(P + i0);
    ushort8v b = *(const ushort8v*)(P + (size_t)n + i0);
    float4 o0, o1;
    o0.x = bf2f(a[0]) + bf2f(b[0]); o0.y = bf2f(a[1]) + bf2f(b[1]);
    o0.z = bf2f(a[2]) + bf2f(b[2]); o0.w = bf2f(a[3]) + bf2f(b[3]);
    o1.x = bf2f(a[4]) + bf2f(b[4]); o1.y = bf2f(a[5]) + bf2f(b[5]);
    o1.z = bf2f(a[6]) + bf2f(b[6]); o1.w = bf2f(a[7]) + bf2f(b[7]);
    *(float4*)(C + i0)     = o0;
    *(float4*)(C + i0 + 4) = o1;
}

// ---- fp32 fallback (tiny ws) ----
__global__ __launch_bounds__(256) void fallback_kernel(const float* __restrict__ x,
                                                       const float* __restrict__ bw,
                                                       const float* __restrict__ sw,
                                                       const float* __restrict__ grid,
                                                       float* __restrict__ out, int Bm) {
    __shared__ float sv[256][QP + 1];
    int b = blockIdx.y;
    int o = blockIdx.x * 256 + threadIdx.x;
    float acc = 0.f;
    for (int ic = 0; ic < IN_F; ic += 256) {
        int i = ic + threadIdx.x;
        float v = x[(size_t)b * IN_F + i];
        float g[12];
        for (int j = 0; j < 12; ++j) g[j] = grid[j];
        float bb[11];
        for (int j = 0; j < 11; ++j) bb[j] = (v >= g[j] && v < g[j + 1]) ? 1.f : 0.f;
        for (int k = 1; k <= 3; ++k)
            for (int j = 0; j < 11 - k; ++j)
                bb[j] = (v - g[j]) / (g[j + k] - g[j] + 1e-8f) * bb[j]
                      + (g[j + k + 1] - v) / (g[j + k + 1] - g[j + 1] + 1e-8f) * bb[j + 1];
        __syncthreads();
        sv[threadIdx.x][0] = v / (1.f + __expf(-v));
        for (int q = 0; q < 8; ++q) sv[threadIdx.x][1 + q] = bb[q];
        __syncthreads();
        for (int ii = 0; ii < 256; ++ii) {
            int i2 = ic + ii;
            acc += sv[ii][0] * bw[(size_t)o * IN_F + i2];
            const float* swp = sw + ((size_t)o * IN_F + i2) * 8;
            for (int q = 0; q < 8; ++q) acc += sv[ii][1 + q] * swp[q];
        }
    }
    out[(size_t)b * OUT_F + o] = acc;
}

extern "C" void kernel_launch(void* const* d_in, const int* in_sizes, int n_in,
                              void* d_out, int out_size, void* d_ws, size_t ws_size,
                              hipStream_t stream) {
    const float* x    = (const float*)d_in[0];
    const float* bw   = (const float*)d_in[1];
    const float* sw   = (const float*)d_in[2];
    const float* grid = (const float*)d_in[3];
    float* out = (float*)d_out;

    const int Bm = in_sizes[0] / IN_F;                     // 4096
    const size_t a_bytes = (size_t)Bm * KDIM * sizeof(__hip_bfloat16);
    const size_t w_bytes = (size_t)OUT_F * KDIM * sizeof(__hip_bfloat16);
    const size_t p_bytes = (size_t)SPLITK * Bm * OUT_F * sizeof(unsigned short);

    if (ws_size >= a_bytes + w_bytes + p_bytes && (Bm % 128) == 0) {
        __hip_bfloat16* Apk = (__hip_bfloat16*)d_ws;
        __hip_bfloat16* Wpk = (__hip_bfloat16*)((char*)d_ws + a_bytes);
        unsigned short* P = (unsigned short*)((char*)d_ws + a_bytes + w_bytes);
        const int nb_a = (Bm * IN_F / 8) / 256;            // 2048
        const int nb_w = (OUT_F * IN_F) / 256;             // 4096
        pack_kernel<<<nb_a + nb_w, 256, 0, stream>>>(x, bw, sw, Apk, Wpk, Bm);
        gemm_splitk<<<dim3(OUT_F / 128, Bm / 128, SPLITK), 256, 0, stream>>>(Apk, Wpk, P, Bm);
        reduce_kernel<<<Bm * OUT_F / 2048, 256, 0, stream>>>(P, out, Bm * OUT_F);
    } else {
        fallback_kernel<<<dim3(OUT_F / 256, Bm), 256, 0, stream>>>(x, bw, sw, grid, out, Bm);
    }
}